// Round 9
// baseline (436.353 us; speedup 1.0000x reference)
//
#include <hip/hip_runtime.h>
#include <hip/hip_bf16.h>
#include <math.h>

#define NN 8192
#define FIN 256
#define FOUT 64
#define LRELU_ALPHA 0.2f
#define TI 16          // rows per attn/wh block (MFMA M)
#define TJ 256         // j-tile width
#define JS 4           // j-range split factor
#define JCHUNK (NN / JS)
#define REPS 3         // DIAGNOSTIC: attn body looped 3x (idempotent) so the
                       // dispatch outlasts the harness 1-GiB fills -> top-5
                       // rocprof visibility. Remove next round.

typedef __attribute__((ext_vector_type(8))) short short8v;
typedef __attribute__((ext_vector_type(4))) float f32x4;

static __device__ inline unsigned short f2bf(float f) {
  __hip_bfloat16 b = __float2bfloat16(f);   // HW cvt
  return *reinterpret_cast<unsigned short*>(&b);
}

// ---------------------------------------------------------------------------
// Fragment layouts (m89-verified family, confirmed by passing r4-r8):
//  A-frag 16x16x32: lane l holds A[m=l&15][k=(l>>4)*8+e], e=0..7
//  B-frag:          lane l holds B[k=(l>>4)*8+e][n=l&15]
//  C/D:             col=l&15, row=(l>>4)*4+reg
// WhF (bf16) for Wh[k][col]:
//  flat = ((k>>5)*4 + (col>>4))*512 + (((k>>3)&3)*16 + (col&15))*8 + (k&7)
// WF (bf16) for W[k][n]: frag (ks,nt): WF[(ks*4+nt)*512 + l*8 + e]
// ---------------------------------------------------------------------------

__global__ __launch_bounds__(256) void gat_prep(
    const float* __restrict__ W, const float* __restrict__ a,
    unsigned short* __restrict__ WF, float* __restrict__ wa1,
    float* __restrict__ wa2) {
  const int t = threadIdx.x;
  if (blockIdx.x < 8) {
    const int wid = blockIdx.x * 4 + (t >> 6);  // == ks*4 + nt
    const int ks = wid >> 2, nt = wid & 3;
    const int l = t & 63;
    const int kg = l >> 4, nn = l & 15;
    unsigned short frag[8];
#pragma unroll
    for (int e = 0; e < 8; ++e) {
      frag[e] = f2bf(W[(ks * 32 + kg * 8 + e) * FOUT + nt * 16 + nn]);
    }
    *(short8v*)&WF[wid * 512 + l * 8] = *(short8v*)frag;
  } else {
    float s1 = 0.f, s2 = 0.f;
#pragma unroll 4
    for (int c = 0; c < FOUT; c += 4) {
      const float4 wv = *(const float4*)&W[t * FOUT + c];
      const float4 a1 = *(const float4*)&a[c];
      const float4 a2 = *(const float4*)&a[FOUT + c];
      s1 += wv.x * a1.x + wv.y * a1.y + wv.z * a1.z + wv.w * a1.w;
      s2 += wv.x * a2.x + wv.y * a2.y + wv.z * a2.z + wv.w * a2.w;
    }
    wa1[t] = s1;
    wa2[t] = s2;
  }
}

__global__ __launch_bounds__(256) void gat_wh5(
    const float* __restrict__ h, const unsigned short* __restrict__ WF,
    const float* __restrict__ wa1, const float* __restrict__ wa2,
    unsigned short* __restrict__ WhF, float* __restrict__ Wh1,
    float* __restrict__ Wh2) {
  __shared__ __align__(16) float hs[TI][260];   // pad 260: 2-way only (free)

  const int t = threadIdx.x;
  const int i0 = blockIdx.x * TI;

#pragma unroll
  for (int q = 0; q < 4; ++q) {
    const int idx = q * 256 + t;
    const float4 v = *(const float4*)&h[(size_t)i0 * FIN + (size_t)idx * 4];
    const int row = idx >> 6, col = (idx & 63) * 4;
    *(float4*)&hs[row][col] = v;
  }
  __syncthreads();

  {
    const int row = t >> 4, s = t & 15;
    float p1 = 0.f, p2 = 0.f;
#pragma unroll
    for (int q = 0; q < 16; ++q) {
      const int k = s + q * 16;
      const float hv = hs[row][k];
      p1 = fmaf(hv, wa1[k], p1);
      p2 = fmaf(hv, wa2[k], p2);
    }
#pragma unroll
    for (int off = 8; off; off >>= 1) {
      p1 += __shfl_xor(p1, off);
      p2 += __shfl_xor(p2, off);
    }
    if (s == 0) {
      Wh1[i0 + row] = p1;
      Wh2[i0 + row] = p2;
    }
  }

  const int w = t >> 6, l = t & 63;
  const int kg = l >> 4, m = l & 15;
  f32x4 acc = {0.f, 0.f, 0.f, 0.f};
#pragma unroll
  for (int ks = 0; ks < 8; ++ks) {
    const float4 fa = *(const float4*)&hs[m][ks * 32 + kg * 8];
    const float4 fb = *(const float4*)&hs[m][ks * 32 + kg * 8 + 4];
    unsigned short af[8];
    af[0] = f2bf(fa.x); af[1] = f2bf(fa.y);
    af[2] = f2bf(fa.z); af[3] = f2bf(fa.w);
    af[4] = f2bf(fb.x); af[5] = f2bf(fb.y);
    af[6] = f2bf(fb.z); af[7] = f2bf(fb.w);
    const short8v bf = *(const short8v*)&WF[(ks * 4 + w) * 512 + l * 8];
    acc =
        __builtin_amdgcn_mfma_f32_16x16x32_bf16(*(short8v*)af, bf, acc, 0, 0, 0);
  }

  const int k0 = i0 + kg * 4;
  const int col = w * 16 + m;
  const int basef = ((k0 >> 5) * 4 + (col >> 4)) * 512 +
                    (((k0 >> 3) & 3) * 16 + (col & 15)) * 8 + (k0 & 7);
  ushort4 st;
  st.x = f2bf(acc[0]);
  st.y = f2bf(acc[1]);
  st.z = f2bf(acc[2]);
  st.w = f2bf(acc[3]);
  *(ushort4*)&WhF[basef] = st;
}

// ---------------------------------------------------------------------------
// Kernel B: structure identical to r6/r8; body looped REPS=3x for rocprof
// visibility (each rep recomputes + rewrites identical num/den).
// ---------------------------------------------------------------------------
__global__ __launch_bounds__(256) void gat_attn4(
    const int* __restrict__ adj, const unsigned short* __restrict__ WhF,
    const float* __restrict__ Wh1, const float* __restrict__ Wh2,
    float* __restrict__ num, float* __restrict__ den) {
  __shared__ __align__(16) unsigned short p_lds[2][TI * TJ];  // 2 x 8 KB
  __shared__ float den_lds[TI];

  const int t = threadIdx.x;
  const int jsplit = blockIdx.x & (JS - 1);
  const int i0 = (blockIdx.x >> 2) * TI;   // JS == 4
  const int j0 = jsplit * JCHUNK;

  const int r0 = t >> 5;           // rows r0, r0+8
  const int col8 = (t & 31) * 8;
  const float w1_0 = Wh1[i0 + r0];
  const float w1_1 = Wh1[i0 + r0 + 8];

  const int w = t >> 6;
  const int l = t & 63;
  const int arow = l & 15;
  const int kg = l >> 4;
  const int colw = w * 16 + arow;

  const int wr0 = ((r0 * TJ + col8) * 2) ^ ((r0 & 7) << 4);
  const int wr1 = (((r0 + 8) * TJ + col8) * 2) ^ ((r0 & 7) << 4);
  const int rdb = (arow * TJ * 2) ^ ((arow & 7) << 4);

  for (int rep = 0; rep < REPS; ++rep) {
    float ds0 = 0.f, ds1 = 0.f;
    f32x4 acc = {0.f, 0.f, 0.f, 0.f};

    int4 a00, a01, a10, a11;
    float4 w2a, w2b;
    {
      const int4* ap0 = (const int4*)&adj[(size_t)(i0 + r0) * NN + j0 + col8];
      const int4* ap1 =
          (const int4*)&adj[(size_t)(i0 + r0 + 8) * NN + j0 + col8];
      a00 = ap0[0]; a01 = ap0[1];
      a10 = ap1[0]; a11 = ap1[1];
      w2a = *(const float4*)&Wh2[j0 + col8];
      w2b = *(const float4*)&Wh2[j0 + col8 + 4];
    }

    for (int jb = j0, it = 0; jb < j0 + JCHUNK; jb += TJ, ++it) {
      unsigned short* pl = &p_lds[it & 1][0];

      const float w2v[8] = {w2a.x, w2a.y, w2a.z, w2a.w,
                            w2b.x, w2b.y, w2b.z, w2b.w};
      const int am0[8] = {a00.x, a00.y, a00.z, a00.w,
                          a01.x, a01.y, a01.z, a01.w};
      const int am1[8] = {a10.x, a10.y, a10.z, a10.w,
                          a11.x, a11.y, a11.z, a11.w};

      short8v pv0, pv1;
#pragma unroll
      for (int e = 0; e < 8; ++e) {
        float v0 = w1_0 + w2v[e];
        v0 = v0 > 0.f ? v0 : LRELU_ALPHA * v0;
        float p0 = (am0[e] > 0) ? __expf(v0) : 0.f;
        ds0 += p0;
        pv0[e] = (short)f2bf(p0);
        float v1 = w1_1 + w2v[e];
        v1 = v1 > 0.f ? v1 : LRELU_ALPHA * v1;
        float p1 = (am1[e] > 0) ? __expf(v1) : 0.f;
        ds1 += p1;
        pv1[e] = (short)f2bf(p1);
      }
      *(short8v*)((char*)pl + wr0) = pv0;
      *(short8v*)((char*)pl + wr1) = pv1;

      if (jb + TJ < j0 + JCHUNK) {
        const int jn = jb + TJ;
        const int4* ap0 = (const int4*)&adj[(size_t)(i0 + r0) * NN + jn + col8];
        const int4* ap1 =
            (const int4*)&adj[(size_t)(i0 + r0 + 8) * NN + jn + col8];
        a00 = ap0[0]; a01 = ap0[1];
        a10 = ap1[0]; a11 = ap1[1];
        w2a = *(const float4*)&Wh2[jn + col8];
        w2b = *(const float4*)&Wh2[jn + col8 + 4];
      }

      asm volatile("s_waitcnt lgkmcnt(0)" ::: "memory");
      __builtin_amdgcn_sched_barrier(0);
      __builtin_amdgcn_s_barrier();

      const int kblk0 = jb >> 5;
#pragma unroll
      for (int kt = 0; kt < 8; ++kt) {
        short8v af = *(const short8v*)((const char*)pl +
                                       (rdb ^ ((kt * 32 + kg * 8) * 2)));
        short8v bf =
            *(const short8v*)&WhF[((kblk0 + kt) * 4 + w) * 512 + l * 8];
        acc = __builtin_amdgcn_mfma_f32_16x16x32_bf16(af, bf, acc, 0, 0, 0);
      }
    }

#pragma unroll
    for (int off = 16; off; off >>= 1) {
      ds0 += __shfl_xor(ds0, off);
      ds1 += __shfl_xor(ds1, off);
    }
    if ((t & 31) == 0) {
      const int rr = t >> 5;
      den_lds[rr] = ds0;
      den_lds[rr + 8] = ds1;
    }
    __syncthreads();
    if (t < TI) den[jsplit * NN + i0 + t] = den_lds[t];

#pragma unroll
    for (int r = 0; r < 4; ++r) {
      num[(size_t)(jsplit * NN + i0 + kg * 4 + r) * FOUT + colw] = acc[r];
    }
    __syncthreads();  // den_lds/p_lds safe before next rep rewrites
  }
}

__global__ __launch_bounds__(256) void gat_comb(
    const float* __restrict__ num, const float* __restrict__ den,
    float* __restrict__ out) {
  const int idx = blockIdx.x * 256 + threadIdx.x;
  const int row = idx >> 6;
  float n = 0.f, d = 0.f;
#pragma unroll
  for (int s = 0; s < JS; ++s) {
    n += num[(size_t)s * NN * FOUT + idx];
    d += den[s * NN + row];
  }
  float v = n / d;
  out[idx] = v > 0.f ? v : expm1f(v);
}

extern "C" void kernel_launch(void* const* d_in, const int* in_sizes, int n_in,
                              void* d_out, int out_size, void* d_ws,
                              size_t ws_size, hipStream_t stream) {
  const float* h = (const float*)d_in[0];
  const int* adj = (const int*)d_in[1];
  const float* W = (const float*)d_in[2];
  const float* a = (const float*)d_in[3];
  float* out = (float*)d_out;

  unsigned short* WhF = (unsigned short*)d_ws;          // 1 MB bf16 fragments
  float* Wh1 = (float*)((char*)d_ws + (1 << 20));       // 32 KB
  float* Wh2 = Wh1 + NN;                                // 32 KB
  float* num = Wh2 + NN;                                // 8 MB
  float* den = num + (size_t)JS * NN * FOUT;            // 128 KB
  unsigned short* WF = (unsigned short*)((char*)d_ws + (16u << 20));  // 32 KB
  float* wa1 = (float*)((char*)d_ws + (16u << 20) + (64u << 10));     // 1 KB
  float* wa2 = wa1 + FIN;                                             // 1 KB

  gat_prep<<<9, 256, 0, stream>>>(W, a, WF, wa1, wa2);
  gat_wh5<<<NN / TI, 256, 0, stream>>>(h, WF, wa1, wa2, WhF, Wh1, Wh2);
  gat_attn4<<<(NN / TI) * JS, 256, 0, stream>>>(adj, WhF, Wh1, Wh2, num, den);
  gat_comb<<<NN * FOUT / 256, 256, 0, stream>>>(num, den, out);
}

// Round 10
// 113.482 us; speedup vs baseline: 3.8451x; 3.8451x over previous
//
#include <hip/hip_runtime.h>
#include <hip/hip_bf16.h>
#include <math.h>

#define NN 8192
#define FIN 256
#define FOUT 64
#define LRELU_ALPHA 0.2f
#define TI 16          // rows per wh block
#define TIB 32         // rows per attn block (32x32 MFMA M)
#define TJ 256         // j-tile width
#define JS 4           // j-range split factor
#define JCHUNK (NN / JS)

typedef __attribute__((ext_vector_type(8))) short short8v;
typedef __attribute__((ext_vector_type(4))) float f32x4;
typedef __attribute__((ext_vector_type(16))) float f32x16;

static __device__ inline unsigned short f2bf(float f) {
  __hip_bfloat16 b = __float2bfloat16(f);   // HW cvt
  return *reinterpret_cast<unsigned short*>(&b);
}

// ---------------------------------------------------------------------------
// Fragment layouts:
//  16x16x32 (wh5): A lane l: A[m=l&15][k=(l>>4)*8+e]; B: B[k=(l>>4)*8+e][n=l&15]
//                  C/D: col=l&15, row=(l>>4)*4+reg            (m89-verified)
//  32x32x16 (attn): A lane l: A[m=l&31][k=(l>>5)*8+e]; B: B[k=(l>>5)*8+e][n=l&31]
//                  C/D: col=l&31, row=(reg&3)+8*(reg>>2)+4*(l>>5) (m74/m101)
//  (any common k-permutation in A/B cancels inside the dot product)
// WhB (bf16): B-frags of Wh per 16-j block:
//  WhB[(jk*2+ch)*512 + l*8 + e] = Wh[jk*16 + (l>>5)*8 + e][ch*32 + (l&31)]
// WF (bf16): W in 16x16x32 B-frag order: WF[(ks*4+nt)*512 + l*8 + e]
// ---------------------------------------------------------------------------

__global__ __launch_bounds__(256) void gat_prep(
    const float* __restrict__ W, const float* __restrict__ a,
    unsigned short* __restrict__ WF, float* __restrict__ wa1,
    float* __restrict__ wa2) {
  const int t = threadIdx.x;
  if (blockIdx.x < 8) {
    const int wid = blockIdx.x * 4 + (t >> 6);  // == ks*4 + nt
    const int ks = wid >> 2, nt = wid & 3;
    const int l = t & 63;
    const int kg = l >> 4, nn = l & 15;
    unsigned short frag[8];
#pragma unroll
    for (int e = 0; e < 8; ++e) {
      frag[e] = f2bf(W[(ks * 32 + kg * 8 + e) * FOUT + nt * 16 + nn]);
    }
    *(short8v*)&WF[wid * 512 + l * 8] = *(short8v*)frag;
  } else {
    float s1 = 0.f, s2 = 0.f;
#pragma unroll 4
    for (int c = 0; c < FOUT; c += 4) {
      const float4 wv = *(const float4*)&W[t * FOUT + c];
      const float4 a1 = *(const float4*)&a[c];
      const float4 a2 = *(const float4*)&a[FOUT + c];
      s1 += wv.x * a1.x + wv.y * a1.y + wv.z * a1.z + wv.w * a1.w;
      s2 += wv.x * a2.x + wv.y * a2.y + wv.z * a2.z + wv.w * a2.w;
    }
    wa1[t] = s1;
    wa2[t] = s2;
  }
}

// ---------------------------------------------------------------------------
// gat_wh6: h-tile -> LDS; Wh1/Wh2 f32 via wa1/wa2; Wh tile via 16x16x32 MFMA;
// store in WhB (32x32 B-frag order for attn). grid 512 x 256.
// ---------------------------------------------------------------------------
__global__ __launch_bounds__(256) void gat_wh6(
    const float* __restrict__ h, const unsigned short* __restrict__ WF,
    const float* __restrict__ wa1, const float* __restrict__ wa2,
    unsigned short* __restrict__ WhB, float* __restrict__ Wh1,
    float* __restrict__ Wh2) {
  __shared__ __align__(16) float hs[TI][260];

  const int t = threadIdx.x;
  const int i0 = blockIdx.x * TI;

#pragma unroll
  for (int q = 0; q < 4; ++q) {
    const int idx = q * 256 + t;
    const float4 v = *(const float4*)&h[(size_t)i0 * FIN + (size_t)idx * 4];
    const int row = idx >> 6, col = (idx & 63) * 4;
    *(float4*)&hs[row][col] = v;
  }
  __syncthreads();

  {
    const int row = t >> 4, s = t & 15;
    float p1 = 0.f, p2 = 0.f;
#pragma unroll
    for (int q = 0; q < 16; ++q) {
      const int k = s + q * 16;
      const float hv = hs[row][k];
      p1 = fmaf(hv, wa1[k], p1);
      p2 = fmaf(hv, wa2[k], p2);
    }
#pragma unroll
    for (int off = 8; off; off >>= 1) {
      p1 += __shfl_xor(p1, off);
      p2 += __shfl_xor(p2, off);
    }
    if (s == 0) {
      Wh1[i0 + row] = p1;
      Wh2[i0 + row] = p2;
    }
  }

  const int w = t >> 6, l = t & 63;
  const int kg = l >> 4, m = l & 15;
  f32x4 acc = {0.f, 0.f, 0.f, 0.f};
#pragma unroll
  for (int ks = 0; ks < 8; ++ks) {
    const float4 fa = *(const float4*)&hs[m][ks * 32 + kg * 8];
    const float4 fb = *(const float4*)&hs[m][ks * 32 + kg * 8 + 4];
    unsigned short af[8];
    af[0] = f2bf(fa.x); af[1] = f2bf(fa.y);
    af[2] = f2bf(fa.z); af[3] = f2bf(fa.w);
    af[4] = f2bf(fb.x); af[5] = f2bf(fb.y);
    af[6] = f2bf(fb.z); af[7] = f2bf(fb.w);
    const short8v bf = *(const short8v*)&WF[(ks * 4 + w) * 512 + l * 8];
    acc =
        __builtin_amdgcn_mfma_f32_16x16x32_bf16(*(short8v*)af, bf, acc, 0, 0, 0);
  }

  // WhB store (verified bijection): acc[r] = Wh[i0+kg*4+r][w*16+m]
  //  jk = i0>>4; lam = (kg>>1)*32 + (w&1)*16 + m; e0 = (kg&1)*4
  {
    const int jk = i0 >> 4;
    const int lam = (kg >> 1) * 32 + (w & 1) * 16 + m;
    const int off = (jk * 2 + (w >> 1)) * 512 + lam * 8 + (kg & 1) * 4;
    ushort4 st;
    st.x = f2bf(acc[0]);
    st.y = f2bf(acc[1]);
    st.z = f2bf(acc[2]);
    st.w = f2bf(acc[3]);
    *(ushort4*)&WhB[off] = st;
  }
}

// ---------------------------------------------------------------------------
// gat_attn5: BARRIER-FREE main loop. grid 1024 = (N/32 rowblocks) x JS.
// Wave w owns j in [jb+64w, jb+64w+64) each tile; lane l computes p for
// row l&31 at k-slots (l>>5)*8+e — exactly its own 32x32x16 A-frag. B from
// WhB (coalesced, L2-hot). acc: 2x f32x16 (col halves). adj reg-prefetch
// depth 2 (ping-pong arrays, static indexing). End: one LDS reduce over the
// 4 waves' disjoint-j partials -> num/den[jsplit].
// ---------------------------------------------------------------------------
__global__ __launch_bounds__(256) void gat_attn5(
    const int* __restrict__ adj, const unsigned short* __restrict__ WhB,
    const float* __restrict__ Wh1, const float* __restrict__ Wh2,
    float* __restrict__ num, float* __restrict__ den) {
  __shared__ float red[4][TIB][FOUT];   // 32 KB
  __shared__ float dred[4][TIB];

  const int t = threadIdx.x;
  const int w = t >> 6, l = t & 63;
  const int row = l & 31, hi = l >> 5;
  const int jsplit = blockIdx.x & (JS - 1);
  const int i0 = (blockIdx.x >> 2) * TIB;   // JS == 4
  const int j0 = jsplit * JCHUNK;
  const int row_g = i0 + row;
  const int* __restrict__ arow = adj + (size_t)row_g * NN;
  const float w1 = Wh1[row_g];
  const int jwb = 64 * w + hi * 8;   // lane's j offset within tile

  f32x16 acc0 = {0.f, 0.f, 0.f, 0.f, 0.f, 0.f, 0.f, 0.f,
                 0.f, 0.f, 0.f, 0.f, 0.f, 0.f, 0.f, 0.f};
  f32x16 acc1 = acc0;
  float dsum = 0.f;

  int4 ajA[8], ajB[8];

#define LOADT(DST, JB)                                              \
  {                                                                 \
    _Pragma("unroll") for (int s = 0; s < 4; ++s) {                 \
      const int4* _p = (const int4*)&arow[(JB) + jwb + s * 16];     \
      DST[2 * s] = _p[0];                                           \
      DST[2 * s + 1] = _p[1];                                       \
    }                                                               \
  }

#define TILE(AJ, JB)                                                          \
  {                                                                           \
    _Pragma("unroll") for (int s = 0; s < 4; ++s) {                           \
      const int jj = (JB) + jwb + s * 16;                                     \
      const float4 w2a = *(const float4*)&Wh2[jj];                            \
      const float4 w2b = *(const float4*)&Wh2[jj + 4];                        \
      const float w2v[8] = {w2a.x, w2a.y, w2a.z, w2a.w,                       \
                            w2b.x, w2b.y, w2b.z, w2b.w};                      \
      const int am[8] = {AJ[2 * s].x,     AJ[2 * s].y,     AJ[2 * s].z,       \
                         AJ[2 * s].w,     AJ[2 * s + 1].x, AJ[2 * s + 1].y,   \
                         AJ[2 * s + 1].z, AJ[2 * s + 1].w};                   \
      short8v af;                                                             \
      _Pragma("unroll") for (int e = 0; e < 8; ++e) {                         \
        float v = w1 + w2v[e];                                                \
        v = v > 0.f ? v : LRELU_ALPHA * v;                                    \
        float p = (am[e] > 0) ? __expf(v) : 0.f;                              \
        dsum += p;                                                            \
        af[e] = (short)f2bf(p);                                               \
      }                                                                       \
      const int jk2 = (((JB) + 64 * w + s * 16) >> 4) * 2;                    \
      const short8v b0 = *(const short8v*)&WhB[(size_t)(jk2 + 0) * 512 + l * 8]; \
      const short8v b1 = *(const short8v*)&WhB[(size_t)(jk2 + 1) * 512 + l * 8]; \
      acc0 = __builtin_amdgcn_mfma_f32_32x32x16_bf16(af, b0, acc0, 0, 0, 0);  \
      acc1 = __builtin_amdgcn_mfma_f32_32x32x16_bf16(af, b1, acc1, 0, 0, 0);  \
    }                                                                         \
  }

  LOADT(ajA, j0);
  // NT = JCHUNK/TJ = 8 tiles, processed in ping-pong pairs (static indexing)
#pragma unroll 1
  for (int it = 0; it < 8; it += 2) {
    const int jb0 = j0 + it * TJ;
    LOADT(ajB, jb0 + TJ);
    TILE(ajA, jb0);
    if (it + 2 < 8) LOADT(ajA, jb0 + 2 * TJ);
    TILE(ajB, jb0 + TJ);
  }
#undef LOADT
#undef TILE

  // ---- cross-wave reduction (waves hold disjoint-j partials) ----
  dsum += __shfl_xor(dsum, 32);
  if (hi == 0) dred[w][row] = dsum;

#pragma unroll
  for (int r = 0; r < 16; ++r) {
    const int orow = (r & 3) + 8 * (r >> 2) + 4 * hi;   // m74/m101 C/D map
    red[w][orow][row] = acc0[r];
    red[w][orow][32 + row] = acc1[r];
  }
  __syncthreads();

  for (int idx = t; idx < TIB * FOUT; idx += 256) {
    const int orow = idx >> 6, oc = idx & 63;
    const float s =
        red[0][orow][oc] + red[1][orow][oc] + red[2][orow][oc] + red[3][orow][oc];
    num[(size_t)(jsplit * NN + i0 + orow) * FOUT + oc] = s;
  }
  if (t < TIB) {
    den[jsplit * NN + i0 + t] =
        dred[0][t] + dred[1][t] + dred[2][t] + dred[3][t];
  }
}

// ---------------------------------------------------------------------------
// Kernel C: out = elu(sum_s num / sum_s den). grid 2048 x 256.
// ---------------------------------------------------------------------------
__global__ __launch_bounds__(256) void gat_comb(
    const float* __restrict__ num, const float* __restrict__ den,
    float* __restrict__ out) {
  const int idx = blockIdx.x * 256 + threadIdx.x;
  const int row = idx >> 6;
  float n = 0.f, d = 0.f;
#pragma unroll
  for (int s = 0; s < JS; ++s) {
    n += num[(size_t)s * NN * FOUT + idx];
    d += den[s * NN + row];
  }
  float v = n / d;
  out[idx] = v > 0.f ? v : expm1f(v);
}

extern "C" void kernel_launch(void* const* d_in, const int* in_sizes, int n_in,
                              void* d_out, int out_size, void* d_ws,
                              size_t ws_size, hipStream_t stream) {
  const float* h = (const float*)d_in[0];
  const int* adj = (const int*)d_in[1];
  const float* W = (const float*)d_in[2];
  const float* a = (const float*)d_in[3];
  float* out = (float*)d_out;

  unsigned short* WhB = (unsigned short*)d_ws;          // 1 MB bf16 B-frags
  float* Wh1 = (float*)((char*)d_ws + (1 << 20));       // 32 KB
  float* Wh2 = Wh1 + NN;                                // 32 KB
  float* num = Wh2 + NN;                                // 8 MB
  float* den = num + (size_t)JS * NN * FOUT;            // 128 KB
  unsigned short* WF = (unsigned short*)((char*)d_ws + (16u << 20));  // 32 KB
  float* wa1 = (float*)((char*)d_ws + (16u << 20) + (64u << 10));     // 1 KB
  float* wa2 = wa1 + FIN;                                             // 1 KB

  gat_prep<<<9, 256, 0, stream>>>(W, a, WF, wa1, wa2);
  gat_wh6<<<NN / TI, 256, 0, stream>>>(h, WF, wa1, wa2, WhB, Wh1, Wh2);
  gat_attn5<<<(NN / TIB) * JS, 256, 0, stream>>>(adj, WhB, Wh1, Wh2, num, den);
  gat_comb<<<NN * FOUT / 256, 256, 0, stream>>>(num, den, out);
}

// Round 11
// 80.185 us; speedup vs baseline: 5.4418x; 1.4152x over previous
//
#include <hip/hip_runtime.h>
#include <hip/hip_bf16.h>
#include <math.h>

#define NN 8192
#define FIN 256
#define FOUT 64
#define LRELU_ALPHA 0.2f
#define TI 16          // rows per block (MFMA M)
#define TJ 256         // j-tile width
#define JS 8           // j-range split factor (occupancy: 4096 blocks)
#define JCHUNK (NN / JS)

typedef __attribute__((ext_vector_type(8))) short short8v;
typedef __attribute__((ext_vector_type(4))) float f32x4;

static __device__ inline unsigned short f2bf(float f) {
  __hip_bfloat16 b = __float2bfloat16(f);   // HW cvt
  return *reinterpret_cast<unsigned short*>(&b);
}

// ---------------------------------------------------------------------------
// Fragment layouts (m89-verified family, confirmed by passing r4-r10):
//  16x16x32: A lane l: A[m=l&15][k=(l>>4)*8+e]; B: B[k=(l>>4)*8+e][n=l&15]
//            C/D: col=l&15, row=(l>>4)*4+reg
// WhF (bf16) for Wh[k][col]:
//  flat = ((k>>5)*4 + (col>>4))*512 + (((k>>3)&3)*16 + (col&15))*8 + (k&7)
// WF (bf16) for W[k][n]: frag (ks,nt): WF[(ks*4+nt)*512 + l*8 + e]
//
// p_lds layout (NEW, conflict-free both sides; for p[m][c], m=0..15 c=0..255):
//  kt=c>>5, kg=(c>>3)&3, e=c&7, sw=(c>>3)&15
//  byte = kt*1024 + kg*256 + ((m ^ sw)<<4) + e*2
//  writer (thread t: rows {t>>5, (t>>5)+8}, cols (t&31)*8..+7): 16B slots at
//   banks 4*(t&7).. -> full 32-bank coverage, 2-way only (free); wr1 = wr0^128
//  reader (MFMA kt): lanes cover contiguous 1KB, each 16B slot once -> free
// ---------------------------------------------------------------------------

__global__ __launch_bounds__(256) void gat_prep(
    const float* __restrict__ W, const float* __restrict__ a,
    unsigned short* __restrict__ WF, float* __restrict__ wa1,
    float* __restrict__ wa2) {
  const int t = threadIdx.x;
  if (blockIdx.x < 8) {
    const int wid = blockIdx.x * 4 + (t >> 6);  // == ks*4 + nt
    const int ks = wid >> 2, nt = wid & 3;
    const int l = t & 63;
    const int kg = l >> 4, nn = l & 15;
    unsigned short frag[8];
#pragma unroll
    for (int e = 0; e < 8; ++e) {
      frag[e] = f2bf(W[(ks * 32 + kg * 8 + e) * FOUT + nt * 16 + nn]);
    }
    *(short8v*)&WF[wid * 512 + l * 8] = *(short8v*)frag;
  } else {
    float s1 = 0.f, s2 = 0.f;
#pragma unroll 4
    for (int c = 0; c < FOUT; c += 4) {
      const float4 wv = *(const float4*)&W[t * FOUT + c];
      const float4 a1 = *(const float4*)&a[c];
      const float4 a2 = *(const float4*)&a[FOUT + c];
      s1 += wv.x * a1.x + wv.y * a1.y + wv.z * a1.z + wv.w * a1.w;
      s2 += wv.x * a2.x + wv.y * a2.y + wv.z * a2.z + wv.w * a2.w;
    }
    wa1[t] = s1;
    wa2[t] = s2;
  }
}

__global__ __launch_bounds__(256) void gat_wh5(
    const float* __restrict__ h, const unsigned short* __restrict__ WF,
    const float* __restrict__ wa1, const float* __restrict__ wa2,
    unsigned short* __restrict__ WhF, float* __restrict__ Wh1,
    float* __restrict__ Wh2) {
  __shared__ __align__(16) float hs[TI][260];

  const int t = threadIdx.x;
  const int i0 = blockIdx.x * TI;

#pragma unroll
  for (int q = 0; q < 4; ++q) {
    const int idx = q * 256 + t;
    const float4 v = *(const float4*)&h[(size_t)i0 * FIN + (size_t)idx * 4];
    const int row = idx >> 6, col = (idx & 63) * 4;
    *(float4*)&hs[row][col] = v;
  }
  __syncthreads();

  {
    const int row = t >> 4, s = t & 15;
    float p1 = 0.f, p2 = 0.f;
#pragma unroll
    for (int q = 0; q < 16; ++q) {
      const int k = s + q * 16;
      const float hv = hs[row][k];
      p1 = fmaf(hv, wa1[k], p1);
      p2 = fmaf(hv, wa2[k], p2);
    }
#pragma unroll
    for (int off = 8; off; off >>= 1) {
      p1 += __shfl_xor(p1, off);
      p2 += __shfl_xor(p2, off);
    }
    if (s == 0) {
      Wh1[i0 + row] = p1;
      Wh2[i0 + row] = p2;
    }
  }

  const int w = t >> 6, l = t & 63;
  const int kg = l >> 4, m = l & 15;
  f32x4 acc = {0.f, 0.f, 0.f, 0.f};
#pragma unroll
  for (int ks = 0; ks < 8; ++ks) {
    const float4 fa = *(const float4*)&hs[m][ks * 32 + kg * 8];
    const float4 fb = *(const float4*)&hs[m][ks * 32 + kg * 8 + 4];
    unsigned short af[8];
    af[0] = f2bf(fa.x); af[1] = f2bf(fa.y);
    af[2] = f2bf(fa.z); af[3] = f2bf(fa.w);
    af[4] = f2bf(fb.x); af[5] = f2bf(fb.y);
    af[6] = f2bf(fb.z); af[7] = f2bf(fb.w);
    const short8v bf = *(const short8v*)&WF[(ks * 4 + w) * 512 + l * 8];
    acc =
        __builtin_amdgcn_mfma_f32_16x16x32_bf16(*(short8v*)af, bf, acc, 0, 0, 0);
  }

  const int k0 = i0 + kg * 4;
  const int col = w * 16 + m;
  const int basef = ((k0 >> 5) * 4 + (col >> 4)) * 512 +
                    (((k0 >> 3) & 3) * 16 + (col & 15)) * 8 + (k0 & 7);
  ushort4 st;
  st.x = f2bf(acc[0]);
  st.y = f2bf(acc[1]);
  st.z = f2bf(acc[2]);
  st.w = f2bf(acc[3]);
  *(ushort4*)&WhF[basef] = st;
}

// ---------------------------------------------------------------------------
// gat_attn6: r8 structure (coalesced adj -> LDS-transposed p -> MFMA),
// JS=8 (4096 blocks, 4 tiles each), conflict-free fragment-ordered p_lds,
// lgkm-only raw barrier, depth-1 reg prefetch.
// ---------------------------------------------------------------------------
__global__ __launch_bounds__(256) void gat_attn6(
    const int* __restrict__ adj, const unsigned short* __restrict__ WhF,
    const float* __restrict__ Wh1, const float* __restrict__ Wh2,
    float* __restrict__ num, float* __restrict__ den) {
  __shared__ __align__(16) unsigned short p_lds[2][TI * TJ];  // 2 x 8 KB
  __shared__ float den_lds[TI];

  const int t = threadIdx.x;
  const int jsplit = blockIdx.x & (JS - 1);
  const int i0 = (blockIdx.x >> 3) * TI;   // JS == 8
  const int j0 = jsplit * JCHUNK;

  // phase-1 identity: rows {r0, r0+8}, cols (t&31)*8..+7
  const int r0 = t >> 5;
  const int col8 = (t & 31) * 8;
  const float w1_0 = Wh1[i0 + r0];
  const float w1_1 = Wh1[i0 + r0 + 8];

  // phase-2 identity
  const int w = t >> 6;
  const int l = t & 63;
  const int arow = l & 15;         // MFMA A row / D col
  const int kg = l >> 4;
  const int colw = w * 16 + arow;

  float ds0 = 0.f, ds1 = 0.f;
  f32x4 acc = {0.f, 0.f, 0.f, 0.f};

  // writer byte offsets in fragment-ordered p_lds
  const int wkt = (t & 31) >> 2, wkg = t & 3, wsw = t & 15;
  const int wr0 = wkt * 1024 + wkg * 256 + (((r0 ^ wsw) & 15) << 4);
  const int wr1 = wr0 ^ 128;   // row+8 flips bit 3 of the slot index

  int4 a00, a01, a10, a11;
  float4 w2a, w2b;
  {
    const int4* ap0 = (const int4*)&adj[(size_t)(i0 + r0) * NN + j0 + col8];
    const int4* ap1 = (const int4*)&adj[(size_t)(i0 + r0 + 8) * NN + j0 + col8];
    a00 = ap0[0]; a01 = ap0[1];
    a10 = ap1[0]; a11 = ap1[1];
    w2a = *(const float4*)&Wh2[j0 + col8];
    w2b = *(const float4*)&Wh2[j0 + col8 + 4];
  }

  for (int jb = j0, it = 0; jb < j0 + JCHUNK; jb += TJ, ++it) {
    unsigned short* pl = &p_lds[it & 1][0];

    const float w2v[8] = {w2a.x, w2a.y, w2a.z, w2a.w,
                          w2b.x, w2b.y, w2b.z, w2b.w};
    const int am0[8] = {a00.x, a00.y, a00.z, a00.w, a01.x, a01.y, a01.z, a01.w};
    const int am1[8] = {a10.x, a10.y, a10.z, a10.w, a11.x, a11.y, a11.z, a11.w};

    short8v pv0, pv1;
#pragma unroll
    for (int e = 0; e < 8; ++e) {
      float v0 = w1_0 + w2v[e];
      v0 = v0 > 0.f ? v0 : LRELU_ALPHA * v0;
      float p0 = (am0[e] > 0) ? __expf(v0) : 0.f;
      ds0 += p0;
      pv0[e] = (short)f2bf(p0);
      float v1 = w1_1 + w2v[e];
      v1 = v1 > 0.f ? v1 : LRELU_ALPHA * v1;
      float p1 = (am1[e] > 0) ? __expf(v1) : 0.f;
      ds1 += p1;
      pv1[e] = (short)f2bf(p1);
    }
    *(short8v*)((char*)pl + wr0) = pv0;
    *(short8v*)((char*)pl + wr1) = pv1;

    // issue next tile's loads (in flight across barrier + MFMA)
    if (jb + TJ < j0 + JCHUNK) {
      const int jn = jb + TJ;
      const int4* ap0 = (const int4*)&adj[(size_t)(i0 + r0) * NN + jn + col8];
      const int4* ap1 =
          (const int4*)&adj[(size_t)(i0 + r0 + 8) * NN + jn + col8];
      a00 = ap0[0]; a01 = ap0[1];
      a10 = ap1[0]; a11 = ap1[1];
      w2a = *(const float4*)&Wh2[jn + col8];
      w2b = *(const float4*)&Wh2[jn + col8 + 4];
    }

    // raw barrier: LDS visibility only, no vmcnt drain
    asm volatile("s_waitcnt lgkmcnt(0)" ::: "memory");
    __builtin_amdgcn_sched_barrier(0);
    __builtin_amdgcn_s_barrier();

    const int kblk0 = jb >> 5;
#pragma unroll
    for (int kt = 0; kt < 8; ++kt) {
      const int swk = (kt * 4 + kg) & 15;
      const int raddr = kt * 1024 + (kg << 8) + ((arow ^ swk) << 4);
      short8v af = *(const short8v*)((const char*)pl + raddr);
      short8v bf = *(const short8v*)&WhF[((kblk0 + kt) * 4 + w) * 512 + l * 8];
      acc = __builtin_amdgcn_mfma_f32_16x16x32_bf16(af, bf, acc, 0, 0, 0);
    }
    // no second barrier: next iteration writes the other p_lds buffer
  }

  // den: half-wave shfl reduce, rows disjoint across waves
#pragma unroll
  for (int off = 16; off; off >>= 1) {
    ds0 += __shfl_xor(ds0, off);
    ds1 += __shfl_xor(ds1, off);
  }
  if ((t & 31) == 0) {
    const int rr = t >> 5;
    den_lds[rr] = ds0;
    den_lds[rr + 8] = ds1;
  }
  __syncthreads();
  if (t < TI) den[(size_t)jsplit * NN + i0 + t] = den_lds[t];

  // num partial: C/D layout col=l&15, row=(l>>4)*4+reg
#pragma unroll
  for (int r = 0; r < 4; ++r) {
    num[((size_t)jsplit * NN + i0 + kg * 4 + r) * FOUT + colw] = acc[r];
  }
}

__global__ __launch_bounds__(256) void gat_comb(
    const float* __restrict__ num, const float* __restrict__ den,
    float* __restrict__ out) {
  const int idx = blockIdx.x * 256 + threadIdx.x;
  const int row = idx >> 6;
  float n = 0.f, d = 0.f;
#pragma unroll
  for (int s = 0; s < JS; ++s) {
    n += num[(size_t)s * NN * FOUT + idx];
    d += den[(size_t)s * NN + row];
  }
  float v = n / d;
  out[idx] = v > 0.f ? v : expm1f(v);
}

extern "C" void kernel_launch(void* const* d_in, const int* in_sizes, int n_in,
                              void* d_out, int out_size, void* d_ws,
                              size_t ws_size, hipStream_t stream) {
  const float* h = (const float*)d_in[0];
  const int* adj = (const int*)d_in[1];
  const float* W = (const float*)d_in[2];
  const float* a = (const float*)d_in[3];
  float* out = (float*)d_out;

  unsigned short* WhF = (unsigned short*)d_ws;          // 1 MB bf16 fragments
  float* Wh1 = (float*)((char*)d_ws + (1 << 20));       // 32 KB
  float* Wh2 = Wh1 + NN;                                // 32 KB
  float* num = Wh2 + NN;                                // JS*2MB = 16 MB
  float* den = num + (size_t)JS * NN * FOUT;            // 256 KB
  unsigned short* WF = (unsigned short*)((char*)d_ws + (24u << 20));  // 32 KB
  float* wa1 = (float*)((char*)d_ws + (24u << 20) + (64u << 10));     // 1 KB
  float* wa2 = wa1 + FIN;                                             // 1 KB

  gat_prep<<<9, 256, 0, stream>>>(W, a, WF, wa1, wa2);
  gat_wh5<<<NN / TI, 256, 0, stream>>>(h, WF, wa1, wa2, WhF, Wh1, Wh2);
  gat_attn6<<<(NN / TI) * JS, 256, 0, stream>>>(adj, WhF, Wh1, Wh2, num, den);
  gat_comb<<<NN * FOUT / 256, 256, 0, stream>>>(num, den, out);
}